// Round 4
// baseline (454.525 us; speedup 1.0000x reference)
//
#include <hip/hip_runtime.h>
#include <stdint.h>

#define DI __device__ __forceinline__

DI float lrelu(float x){ return x >= 0.0f ? x : 0.01f*x; }

// ---------------- threefry2x32, JAX key(42) => (0, 42) ----------------
DI uint32_t rotl32(uint32_t x, int d){ return (x << d) | (x >> (32 - d)); }

DI void threefry_0_42(uint32_t& x0, uint32_t& x1){
  const uint32_t ks0 = 0u, ks1 = 42u, ks2 = 0x1BD11BF0u; // 0 ^ 42 ^ 0x1BD11BDA
  x0 += ks0; x1 += ks1;
  #define TFR(d) { x0 += x1; x1 = rotl32(x1,(d)); x1 ^= x0; }
  TFR(13) TFR(15) TFR(26) TFR(6)  x0 += ks1; x1 += ks2 + 1u;
  TFR(17) TFR(29) TFR(16) TFR(24) x0 += ks2; x1 += ks0 + 2u;
  TFR(13) TFR(15) TFR(26) TFR(6)  x0 += ks0; x1 += ks1 + 3u;
  TFR(17) TFR(29) TFR(16) TFR(24) x0 += ks1; x1 += ks2 + 4u;
  TFR(13) TFR(15) TFR(26) TFR(6)  x0 += ks2; x1 += ks0 + 5u;
  #undef TFR
}

// XLA/Giles single-precision erfinv (same coefficients as chlo erf_inv f32)
DI float erfinv_f32(float x){
  float w = -log1pf(-x*x);
  float p;
  if (w < 5.0f){
    w = w - 2.5f;
    p = 2.81022636e-08f;
    p = fmaf(p, w, 3.43273939e-07f);
    p = fmaf(p, w, -3.5233877e-06f);
    p = fmaf(p, w, -4.39150654e-06f);
    p = fmaf(p, w, 0.00021858087f);
    p = fmaf(p, w, -0.00125372503f);
    p = fmaf(p, w, -0.00417768164f);
    p = fmaf(p, w, 0.246640727f);
    p = fmaf(p, w, 1.50140941f);
  } else {
    w = sqrtf(w) - 3.0f;
    p = -0.000200214257f;
    p = fmaf(p, w, 0.000100950558f);
    p = fmaf(p, w, 0.00134934322f);
    p = fmaf(p, w, -0.00367342844f);
    p = fmaf(p, w, 0.00573950773f);
    p = fmaf(p, w, -0.0076224613f);
    p = fmaf(p, w, 0.00943887047f);
    p = fmaf(p, w, 1.00167406f);
    p = fmaf(p, w, 2.83297682f);
  }
  return p * x;
}

// out offsets (floats)
#define OUT_D_OFF   0
#define OUT_MU_OFF  12288000
#define OUT_LV_OFF  (12288000 + 3840)
#define OUT_Z_OFF   (12288000 + 7680)

// =====================================================================
// enc1: conv(x,w1,SAME 3x3, 6->8)+lrelu+maxpool 2x2 -> p1[32,8,250,64]
// LDS tile band: 8 conv rows (+2 halo) x full 128 cols (+2 halo), 6 ch.
// 256 thr = 64 pooled cols x 4 pooled rows. grid = 63 bands x 32 batch.
__global__ __launch_bounds__(256) void k_enc1(const float* __restrict__ x,
                                              const float* __restrict__ w1,
                                              float* __restrict__ p1){
  __shared__ float tile[6*10*130]; // 31200 floats
  int tid = threadIdx.x;
  int band = blockIdx.x % 63;
  int b    = blockIdx.x / 63;
  int r0 = band*8;
  for (int idx = tid; idx < 6*10*130; idx += 256){
    int lc = idx % 130;
    int rest = idx / 130;
    int lr = rest % 10;
    int ch = rest / 10;
    int gr = r0 - 1 + lr, gc = lc - 1;
    float v = 0.0f;
    if ((unsigned)gr < 500u && (unsigned)gc < 128u)
      v = x[((b*6+ch)*500+gr)*128+gc];
    tile[idx] = v;
  }
  __syncthreads();
  int pw = tid & 63, pr = tid >> 6;
  int ph = band*4 + pr;
  float acc[2][2][8];
  #pragma unroll
  for (int a=0;a<2;a++)
    #pragma unroll
    for (int d=0;d<2;d++)
      #pragma unroll
      for (int o=0;o<8;o++) acc[a][d][o] = 0.0f;
  int base = (2*pr)*130 + 2*pw;
  #pragma unroll 2
  for (int c = 0; c < 6; ++c){
    float win[4][4];
    #pragma unroll
    for (int i=0;i<4;i++)
      #pragma unroll
      for (int j=0;j<4;j++)
        win[i][j] = tile[c*1300 + base + i*130 + j];
    #pragma unroll
    for (int kh=0;kh<3;kh++)
      #pragma unroll
      for (int kw=0;kw<3;kw++){
        float wv[8];
        #pragma unroll
        for (int o=0;o<8;o++) wv[o] = w1[((o*6+c)*3+kh)*3+kw];
        #pragma unroll
        for (int dy=0;dy<2;dy++)
          #pragma unroll
          for (int dx=0;dx<2;dx++){
            float v = win[dy+kh][dx+kw];
            #pragma unroll
            for (int o=0;o<8;o++) acc[dy][dx][o] = fmaf(v, wv[o], acc[dy][dx][o]);
          }
      }
  }
  if (ph < 250){
    #pragma unroll
    for (int o=0;o<8;o++){
      float m = fmaxf(fmaxf(acc[0][0][o], acc[0][1][o]), fmaxf(acc[1][0][o], acc[1][1][o]));
      p1[((b*8+o)*250+ph)*64+pw] = lrelu(m);
    }
  }
}

// =====================================================================
// enc2: conv(p1,w2,SAME 3x3, 8->16)+lrelu+maxpool(5,2) -> p2[32,16,50,32]
// LDS tile band: 20 conv rows (+2) x 64 cols (+2), 8 ch. 256 thr =
// (32 pw x 2 dx) x 4 pooled rows. grid = 13 bands x 32 batch.
__global__ __launch_bounds__(256) void k_enc2(const float* __restrict__ in,
                                              const float* __restrict__ w2,
                                              float* __restrict__ p2){
  __shared__ float tile[8*22*66]; // 11616 floats
  int tid = threadIdx.x;
  int band = blockIdx.x % 13;
  int b    = blockIdx.x / 13;
  int r0 = band*20;
  for (int idx = tid; idx < 8*22*66; idx += 256){
    int lc = idx % 66;
    int rest = idx / 66;
    int lr = rest % 22;
    int ch = rest / 22;
    int gr = r0 - 1 + lr, gc = lc - 1;
    float v = 0.0f;
    if ((unsigned)gr < 250u && (unsigned)gc < 64u)
      v = in[((b*8+ch)*250+gr)*64+gc];
    tile[idx] = v;
  }
  __syncthreads();
  int dx = tid & 1; int u = tid >> 1;
  int pw = u & 31; int pr = (u >> 5) & 3;
  int cw = 2*pw + dx;
  int ph = band*4 + pr;
  float acc[5][16];
  #pragma unroll
  for (int dy=0;dy<5;dy++)
    #pragma unroll
    for (int o=0;o<16;o++) acc[dy][o] = 0.0f;
  int base = (5*pr)*66 + cw;
  #pragma unroll 1
  for (int c = 0; c < 8; ++c){
    float win[7][3];
    #pragma unroll
    for (int i=0;i<7;i++)
      #pragma unroll
      for (int j=0;j<3;j++)
        win[i][j] = tile[c*1452 + base + i*66 + j];
    #pragma unroll
    for (int kh=0;kh<3;kh++)
      #pragma unroll
      for (int kw=0;kw<3;kw++){
        float wv[16];
        #pragma unroll
        for (int o=0;o<16;o++) wv[o] = w2[((o*8+c)*3+kh)*3+kw];
        #pragma unroll
        for (int dy=0;dy<5;dy++){
          float v = win[dy+kh][kw];
          #pragma unroll
          for (int o=0;o<16;o++) acc[dy][o] = fmaf(v, wv[o], acc[dy][o]);
        }
      }
  }
  #pragma unroll
  for (int o=0;o<16;o++){
    float m = acc[0][o];
    #pragma unroll
    for (int dy=1;dy<5;dy++) m = fmaxf(m, acc[dy][o]);
    m = fmaxf(m, __shfl_xor(m, 1));
    if (dx == 0 && ph < 50) p2[((b*16+o)*50+ph)*32+pw] = lrelu(m);
  }
}

// =====================================================================
// conv3: conv(p2,w3,SAME 3x3, 16->32)+lrelu -> h3[32,32,50,32]
// LDS tile: 8 rows (+2) x 32 cols (+2), 16 ch. 256 thr = 32 col x 8 row.
// grid = 7 bands x 2 oh x 32 batch.
__global__ __launch_bounds__(256) void k_conv3(const float* __restrict__ in,
                                               const float* __restrict__ w3,
                                               float* __restrict__ outp){
  __shared__ float tile[16*10*34]; // 5440 floats
  int tid = threadIdx.x;
  int bi = blockIdx.x;
  int band = bi % 7; int oh = (bi/7) & 1; int b = bi / 14;
  int r0 = band*8;
  for (int idx = tid; idx < 16*10*34; idx += 256){
    int lc = idx % 34;
    int rest = idx / 34;
    int lr = rest % 10;
    int ch = rest / 10;
    int gr = r0 - 1 + lr, gc = lc - 1;
    float v = 0.0f;
    if ((unsigned)gr < 50u && (unsigned)gc < 32u)
      v = in[((b*16+ch)*50+gr)*32+gc];
    tile[idx] = v;
  }
  __syncthreads();
  int col = tid & 31, tr = tid >> 5;
  int h = r0 + tr;
  float acc[16];
  #pragma unroll
  for (int o=0;o<16;o++) acc[o] = 0.0f;
  int base = tr*34 + col;
  #pragma unroll 2
  for (int c = 0; c < 16; ++c){
    float win[3][3];
    #pragma unroll
    for (int i=0;i<3;i++)
      #pragma unroll
      for (int j=0;j<3;j++)
        win[i][j] = tile[c*340 + base + i*34 + j];
    #pragma unroll
    for (int kh=0;kh<3;kh++)
      #pragma unroll
      for (int kw=0;kw<3;kw++){
        float v = win[kh][kw];
        #pragma unroll
        for (int o=0;o<16;o++)
          acc[o] = fmaf(v, w3[(((oh*16+o)*16+c)*3+kh)*3+kw], acc[o]);
      }
  }
  if (h < 50){
    #pragma unroll
    for (int o=0;o<16;o++)
      outp[((b*32 + oh*16 + o)*50 + h)*32 + col] = lrelu(acc[o]);
  }
}

// =====================================================================
// pool3: maxpool(5,2) on h3 -> p3[32,32,10,16]
__global__ __launch_bounds__(256) void k_pool3(const float* __restrict__ in,
                                               float* __restrict__ outp){
  int t = blockIdx.x*256 + threadIdx.x;
  int pw = t & 15; int u = t >> 4; int ph = u % 10; u /= 10; int o = u & 31; int b = u >> 5;
  float m = -INFINITY;
  #pragma unroll
  for (int dh=0;dh<5;dh++)
    #pragma unroll
    for (int dw=0;dw<2;dw++)
      m = fmaxf(m, in[((b*32+o)*50 + 5*ph+dh)*32 + 2*pw+dw]);
  outp[((b*32+o)*10+ph)*16+pw] = m;
}

// =====================================================================
// latent: mu/logvar conv (1,5) VALID 32->1, reparameterize with threefry eps
// eps uses JAX *partitionable* threefry: per element t,
//   (y0,y1) = threefry(key=(0,42), counter=(0,t)); bits = y0 ^ y1.
__global__ __launch_bounds__(256) void k_latent(const float* __restrict__ p3,
                                                const float* __restrict__ wmu,
                                                const float* __restrict__ wlv,
                                                float* __restrict__ outp){
  int t = blockIdx.x*256 + threadIdx.x; // 3840 total
  int w = t % 12; int h = (t/12) % 10; int b = t/120;
  float mu = 0.0f, lv = 0.0f;
  for (int c = 0; c < 32; ++c){
    const float* row = p3 + ((b*32+c)*10+h)*16 + w;
    #pragma unroll
    for (int kw=0;kw<5;kw++){
      float v = row[kw];
      mu = fmaf(v, wmu[c*5+kw], mu);
      lv = fmaf(v, wlv[c*5+kw], lv);
    }
  }
  uint32_t x0 = 0u, x1 = (uint32_t)t;
  threefry_0_42(x0, x1);
  uint32_t bits = x0 ^ x1;
  float f = __uint_as_float((bits >> 9) | 0x3f800000u) - 1.0f; // [0,1)
  const float lo = -0.99999994f; // nextafter(-1,0) in f32; (1-lo) rounds to 2.0f
  float uu = fmaxf(lo, f * 2.0f + lo);
  float eps = 1.41421356f * erfinv_f32(uu);
  float z = mu + eps * expf(0.5f * lv);
  outp[OUT_MU_OFF + t] = mu;
  outp[OUT_LV_OFF + t] = lv;
  outp[OUT_Z_OFF  + t] = z;
}

// =====================================================================
// dec0: convT(z, wu0[32,1,1,5], stride 1, VALID) + lrelu -> d0[32,32,10,16]
__global__ __launch_bounds__(256) void k_dec0(const float* __restrict__ outp, // d_out base (z lives there)
                                              const float* __restrict__ wu0,
                                              float* __restrict__ d0){
  int t = blockIdx.x*256 + threadIdx.x;
  int w = t & 15; int u = t >> 4; int h = u % 10; u /= 10; int o = u & 31; int b = u >> 5;
  const float* z = outp + OUT_Z_OFF;
  float a = 0.0f;
  #pragma unroll
  for (int kw=0;kw<5;kw++){
    int ww = w + kw - 4;
    if ((unsigned)ww < 12u) a = fmaf(z[b*120 + h*12 + ww], wu0[o*5+kw], a);
  }
  d0[((b*32+o)*10+h)*16+w] = lrelu(a);
}

// =====================================================================
// dec1: convT(d0, wu1[32,32,5,2], strides (5,2)) + lrelu -> d1[32,32,50,32]
// kernel==stride: out[o,5i+r,2j+s] = sum_c d0[c,i,j]*wu1[o,c,4-r,1-s]
__global__ __launch_bounds__(256) void k_dec1(const float* __restrict__ d0,
                                              const float* __restrict__ wu1,
                                              float* __restrict__ d1){
  int t = blockIdx.x*256 + threadIdx.x;
  int wo = t & 31; int u = t >> 5; int ho = u % 50; u /= 50; int o = u & 31; int b = u >> 5;
  int i = ho / 5, r = ho - 5*i, jj = wo >> 1, s = wo & 1;
  const float* ip = d0 + b*5120 + i*16 + jj;             // + c*160
  const float* wp = wu1 + (o*32*5 + (4-r))*2 + (1-s);    // + c*10
  float a = 0.0f;
  #pragma unroll 8
  for (int c=0;c<32;c++) a = fmaf(ip[c*160], wp[c*10], a);
  d1[((b*32+o)*50+ho)*32+wo] = lrelu(a);
}

// =====================================================================
// c4: conv(d1, w4[16,32,3,3], SAME)+lrelu -> d2[32,16,50,32]
// LDS tile: 8 rows (+2) x 32 cols (+2), 32 ch. grid = 7 x 2 oh x 32.
__global__ __launch_bounds__(256) void k_c4(const float* __restrict__ in,
                                            const float* __restrict__ w4,
                                            float* __restrict__ outp){
  __shared__ float tile[32*10*34]; // 10880 floats
  int tid = threadIdx.x;
  int bi = blockIdx.x;
  int band = bi % 7; int oh = (bi/7) & 1; int b = bi / 14;
  int r0 = band*8;
  for (int idx = tid; idx < 32*10*34; idx += 256){
    int lc = idx % 34;
    int rest = idx / 34;
    int lr = rest % 10;
    int ch = rest / 10;
    int gr = r0 - 1 + lr, gc = lc - 1;
    float v = 0.0f;
    if ((unsigned)gr < 50u && (unsigned)gc < 32u)
      v = in[((b*32+ch)*50+gr)*32+gc];
    tile[idx] = v;
  }
  __syncthreads();
  int col = tid & 31, tr = tid >> 5;
  int h = r0 + tr;
  float acc[8];
  #pragma unroll
  for (int o=0;o<8;o++) acc[o] = 0.0f;
  int base = tr*34 + col;
  #pragma unroll 2
  for (int c = 0; c < 32; ++c){
    float win[3][3];
    #pragma unroll
    for (int i=0;i<3;i++)
      #pragma unroll
      for (int j=0;j<3;j++)
        win[i][j] = tile[c*340 + base + i*34 + j];
    #pragma unroll
    for (int kh=0;kh<3;kh++)
      #pragma unroll
      for (int kw=0;kw<3;kw++){
        float v = win[kh][kw];
        #pragma unroll
        for (int o=0;o<8;o++)
          acc[o] = fmaf(v, w4[(((oh*8+o)*32+c)*3+kh)*3+kw], acc[o]);
      }
  }
  if (h < 50){
    #pragma unroll
    for (int o=0;o<8;o++)
      outp[((b*16 + oh*8 + o)*50 + h)*32 + col] = lrelu(acc[o]);
  }
}

// =====================================================================
// u2: convT(d2, wu2[16,16,5,2], strides (5,2)) + lrelu -> d3[32,16,250,64]
__global__ __launch_bounds__(256) void k_u2(const float* __restrict__ d2,
                                            const float* __restrict__ wu2,
                                            float* __restrict__ d3){
  int t = blockIdx.x*256 + threadIdx.x;
  int w = t & 63; int u = t >> 6; int h = u % 250; u /= 250; int o = u & 15; int b = u >> 4;
  int i = h / 5, r = h - 5*i, jj = w >> 1, s = w & 1;
  const float* ip = d2 + b*25600 + i*32 + jj;            // + c*1600
  const float* wp = wu2 + (o*16*5 + (4-r))*2 + (1-s);    // + c*10
  float a = 0.0f;
  #pragma unroll 8
  for (int c=0;c<16;c++) a = fmaf(ip[c*1600], wp[c*10], a);
  d3[((b*16+o)*250+h)*64+w] = lrelu(a);
}

// =====================================================================
// c5: conv(d3, w5[8,16,3,3], SAME)+lrelu -> d4[32,8,250,64]
// LDS tile: 4 rows (+2) x 64 cols (+2), 16 ch. grid = 63 bands x 32.
__global__ __launch_bounds__(256) void k_c5(const float* __restrict__ in,
                                            const float* __restrict__ w5,
                                            float* __restrict__ outp){
  __shared__ float tile[16*6*66]; // 6336 floats
  int tid = threadIdx.x;
  int band = blockIdx.x % 63;
  int b    = blockIdx.x / 63;
  int r0 = band*4;
  for (int idx = tid; idx < 16*6*66; idx += 256){
    int lc = idx % 66;
    int rest = idx / 66;
    int lr = rest % 6;
    int ch = rest / 6;
    int gr = r0 - 1 + lr, gc = lc - 1;
    float v = 0.0f;
    if ((unsigned)gr < 250u && (unsigned)gc < 64u)
      v = in[((b*16+ch)*250+gr)*64+gc];
    tile[idx] = v;
  }
  __syncthreads();
  int col = tid & 63, tr = tid >> 6;
  int h = r0 + tr;
  float acc[8];
  #pragma unroll
  for (int o=0;o<8;o++) acc[o] = 0.0f;
  int base = tr*66 + col;
  #pragma unroll 2
  for (int c = 0; c < 16; ++c){
    float win[3][3];
    #pragma unroll
    for (int i=0;i<3;i++)
      #pragma unroll
      for (int j=0;j<3;j++)
        win[i][j] = tile[c*396 + base + i*66 + j];
    #pragma unroll
    for (int kh=0;kh<3;kh++)
      #pragma unroll
      for (int kw=0;kw<3;kw++){
        float v = win[kh][kw];
        #pragma unroll
        for (int o=0;o<8;o++)
          acc[o] = fmaf(v, w5[((o*16+c)*3+kh)*3+kw], acc[o]);
      }
  }
  if (h < 250){
    #pragma unroll
    for (int o=0;o<8;o++)
      outp[((b*8+o)*250+h)*64+col] = lrelu(acc[o]);
  }
}

// =====================================================================
// u3: convT(d4, wu3[8,8,2,2], strides (2,2)) + lrelu -> d5[32,8,500,128]
__global__ __launch_bounds__(256) void k_u3(const float* __restrict__ d4,
                                            const float* __restrict__ wu3,
                                            float* __restrict__ d5){
  int t = blockIdx.x*256 + threadIdx.x;
  int w = t & 127; int u = t >> 7; int h = u % 500; u /= 500; int o = u & 7; int b = u >> 3;
  int i = h >> 1, r = h & 1, jj = w >> 1, s = w & 1;
  const float* ip = d4 + b*128000 + i*64 + jj;           // + c*16000
  const float* wp = wu3 + (o*8*2 + (1-r))*2 + (1-s);     // + c*4
  float a = 0.0f;
  #pragma unroll
  for (int c=0;c<8;c++) a = fmaf(ip[c*16000], wp[c*4], a);
  d5[((b*8+o)*500+h)*128+w] = lrelu(a);
}

// =====================================================================
// c6: conv(d5, w6[6,8,3,3], SAME)+lrelu -> d_out[32,6,500,128]
// LDS tile: 2 rows (+2) x 128 cols (+2), 8 ch. grid = 250 bands x 32.
__global__ __launch_bounds__(256) void k_c6(const float* __restrict__ in,
                                            const float* __restrict__ w6,
                                            float* __restrict__ outp){
  __shared__ float tile[8*4*130]; // 4160 floats
  int tid = threadIdx.x;
  int band = blockIdx.x % 250;
  int b    = blockIdx.x / 250;
  int r0 = band*2;
  for (int idx = tid; idx < 8*4*130; idx += 256){
    int lc = idx % 130;
    int rest = idx / 130;
    int lr = rest & 3;
    int ch = rest >> 2;
    int gr = r0 - 1 + lr, gc = lc - 1;
    float v = 0.0f;
    if ((unsigned)gr < 500u && (unsigned)gc < 128u)
      v = in[((b*8+ch)*500+gr)*128+gc];
    tile[idx] = v;
  }
  __syncthreads();
  int col = tid & 127, tr = tid >> 7;
  int h = r0 + tr;
  float acc[6];
  #pragma unroll
  for (int o=0;o<6;o++) acc[o] = 0.0f;
  int base = tr*130 + col;
  #pragma unroll 2
  for (int c = 0; c < 8; ++c){
    float win[3][3];
    #pragma unroll
    for (int i=0;i<3;i++)
      #pragma unroll
      for (int j=0;j<3;j++)
        win[i][j] = tile[c*520 + base + i*130 + j];
    #pragma unroll
    for (int kh=0;kh<3;kh++)
      #pragma unroll
      for (int kw=0;kw<3;kw++){
        float v = win[kh][kw];
        #pragma unroll
        for (int o=0;o<6;o++)
          acc[o] = fmaf(v, w6[((o*8+c)*3+kh)*3+kw], acc[o]);
      }
  }
  #pragma unroll
  for (int o=0;o<6;o++)
    outp[((b*6+o)*500+h)*128+col] = lrelu(acc[o]);
}

// =====================================================================
extern "C" void kernel_launch(void* const* d_in, const int* in_sizes, int n_in,
                              void* d_out, int out_size, void* d_ws, size_t ws_size,
                              hipStream_t stream){
  const float* x   = (const float*)d_in[0];
  const float* w1  = (const float*)d_in[1];
  const float* w2  = (const float*)d_in[2];
  const float* w3  = (const float*)d_in[3];
  const float* wmu = (const float*)d_in[4];
  const float* wlv = (const float*)d_in[5];
  const float* wu0 = (const float*)d_in[6];
  const float* wu1 = (const float*)d_in[7];
  const float* w4  = (const float*)d_in[8];
  const float* wu2 = (const float*)d_in[9];
  const float* w5  = (const float*)d_in[10];
  const float* wu3 = (const float*)d_in[11];
  const float* w6  = (const float*)d_in[12];
  float* out = (float*)d_out;
  float* A  = (float*)d_ws;          // 4,096,000 floats arena
  float* Bb = A + 4096000;           // 16,384,000 floats arena

  k_enc1 <<<2016, 256, 0, stream>>>(x,  w1,  A);   // p1 [32,8,250,64]
  k_enc2 <<< 416, 256, 0, stream>>>(A,  w2,  Bb);  // p2 [32,16,50,32]
  k_conv3<<< 448, 256, 0, stream>>>(Bb, w3,  A);   // h3 [32,32,50,32]
  k_pool3<<< 640, 256, 0, stream>>>(A,  Bb);       // p3 [32,32,10,16]
  k_latent<<< 15, 256, 0, stream>>>(Bb, wmu, wlv, out); // mu/lv/z -> d_out
  k_dec0 <<< 640, 256, 0, stream>>>(out, wu0, A);  // d0 [32,32,10,16]
  k_dec1 <<<6400, 256, 0, stream>>>(A,  wu1, Bb);  // d1 [32,32,50,32]
  k_c4   <<< 448, 256, 0, stream>>>(Bb, w4,  A);   // d2 [32,16,50,32]
  k_u2   <<<32000,256, 0, stream>>>(A,  wu2, Bb);  // d3 [32,16,250,64]
  k_c5   <<<2016, 256, 0, stream>>>(Bb, w5,  A);   // d4 [32,8,250,64]
  k_u3   <<<64000,256, 0, stream>>>(A,  wu3, Bb);  // d5 [32,8,500,128]
  k_c6   <<<8000, 256, 0, stream>>>(Bb, w6,  out); // d  [32,6,500,128]
}

// Round 5
// 432.243 us; speedup vs baseline: 1.0516x; 1.0516x over previous
//
#include <hip/hip_runtime.h>
#include <stdint.h>

#define DI __device__ __forceinline__

DI float lrelu(float x){ return x >= 0.0f ? x : 0.01f*x; }

// ---------------- threefry2x32, JAX key(42) => (0, 42) ----------------
DI uint32_t rotl32(uint32_t x, int d){ return (x << d) | (x >> (32 - d)); }

DI void threefry_0_42(uint32_t& x0, uint32_t& x1){
  const uint32_t ks0 = 0u, ks1 = 42u, ks2 = 0x1BD11BF0u; // 0 ^ 42 ^ 0x1BD11BDA
  x0 += ks0; x1 += ks1;
  #define TFR(d) { x0 += x1; x1 = rotl32(x1,(d)); x1 ^= x0; }
  TFR(13) TFR(15) TFR(26) TFR(6)  x0 += ks1; x1 += ks2 + 1u;
  TFR(17) TFR(29) TFR(16) TFR(24) x0 += ks2; x1 += ks0 + 2u;
  TFR(13) TFR(15) TFR(26) TFR(6)  x0 += ks0; x1 += ks1 + 3u;
  TFR(17) TFR(29) TFR(16) TFR(24) x0 += ks1; x1 += ks2 + 4u;
  TFR(13) TFR(15) TFR(26) TFR(6)  x0 += ks2; x1 += ks0 + 5u;
  #undef TFR
}

// XLA/Giles single-precision erfinv (same coefficients as chlo erf_inv f32)
DI float erfinv_f32(float x){
  float w = -log1pf(-x*x);
  float p;
  if (w < 5.0f){
    w = w - 2.5f;
    p = 2.81022636e-08f;
    p = fmaf(p, w, 3.43273939e-07f);
    p = fmaf(p, w, -3.5233877e-06f);
    p = fmaf(p, w, -4.39150654e-06f);
    p = fmaf(p, w, 0.00021858087f);
    p = fmaf(p, w, -0.00125372503f);
    p = fmaf(p, w, -0.00417768164f);
    p = fmaf(p, w, 0.246640727f);
    p = fmaf(p, w, 1.50140941f);
  } else {
    w = sqrtf(w) - 3.0f;
    p = -0.000200214257f;
    p = fmaf(p, w, 0.000100950558f);
    p = fmaf(p, w, 0.00134934322f);
    p = fmaf(p, w, -0.00367342844f);
    p = fmaf(p, w, 0.00573950773f);
    p = fmaf(p, w, -0.0076224613f);
    p = fmaf(p, w, 0.00943887047f);
    p = fmaf(p, w, 1.00167406f);
    p = fmaf(p, w, 2.83297682f);
  }
  return p * x;
}

// out offsets (floats)
#define OUT_D_OFF   0
#define OUT_MU_OFF  12288000
#define OUT_LV_OFF  (12288000 + 3840)
#define OUT_Z_OFF   (12288000 + 7680)

// =====================================================================
// enc1: conv(x,w1,SAME 3x3, 6->8)+lrelu+maxpool 2x2 -> p1[32,8,250,64]
// LDS tile band: 8 conv rows (+2 halo) x full 128 cols (+2 halo), 6 ch.
// 256 thr = 64 pooled cols x 4 pooled rows. grid = 63 bands x 32 batch.
__global__ __launch_bounds__(256) void k_enc1(const float* __restrict__ x,
                                              const float* __restrict__ w1,
                                              float* __restrict__ p1){
  __shared__ float tile[6*10*130]; // 7800 floats
  int tid = threadIdx.x;
  int band = blockIdx.x % 63;
  int b    = blockIdx.x / 63;
  int r0 = band*8;
  for (int idx = tid; idx < 6*10*130; idx += 256){
    int lc = idx % 130;
    int rest = idx / 130;
    int lr = rest % 10;
    int ch = rest / 10;
    int gr = r0 - 1 + lr, gc = lc - 1;
    float v = 0.0f;
    if ((unsigned)gr < 500u && (unsigned)gc < 128u)
      v = x[((b*6+ch)*500+gr)*128+gc];
    tile[idx] = v;
  }
  __syncthreads();
  int pw = tid & 63, pr = tid >> 6;
  int ph = band*4 + pr;
  float acc[2][2][8];
  #pragma unroll
  for (int a=0;a<2;a++)
    #pragma unroll
    for (int d=0;d<2;d++)
      #pragma unroll
      for (int o=0;o<8;o++) acc[a][d][o] = 0.0f;
  int base = (2*pr)*130 + 2*pw;
  #pragma unroll 2
  for (int c = 0; c < 6; ++c){
    float win[4][4];
    #pragma unroll
    for (int i=0;i<4;i++)
      #pragma unroll
      for (int j=0;j<4;j++)
        win[i][j] = tile[c*1300 + base + i*130 + j];
    #pragma unroll
    for (int kh=0;kh<3;kh++)
      #pragma unroll
      for (int kw=0;kw<3;kw++){
        float wv[8];
        #pragma unroll
        for (int o=0;o<8;o++) wv[o] = w1[((o*6+c)*3+kh)*3+kw];
        #pragma unroll
        for (int dy=0;dy<2;dy++)
          #pragma unroll
          for (int dx=0;dx<2;dx++){
            float v = win[dy+kh][dx+kw];
            #pragma unroll
            for (int o=0;o<8;o++) acc[dy][dx][o] = fmaf(v, wv[o], acc[dy][dx][o]);
          }
      }
  }
  if (ph < 250){
    #pragma unroll
    for (int o=0;o<8;o++){
      float m = fmaxf(fmaxf(acc[0][0][o], acc[0][1][o]), fmaxf(acc[1][0][o], acc[1][1][o]));
      p1[((b*8+o)*250+ph)*64+pw] = lrelu(m);
    }
  }
}

// =====================================================================
// enc2: conv(p1,w2,SAME 3x3, 8->16)+lrelu+maxpool(5,2) -> p2[32,16,50,32]
__global__ __launch_bounds__(256) void k_enc2(const float* __restrict__ in,
                                              const float* __restrict__ w2,
                                              float* __restrict__ p2){
  __shared__ float tile[8*22*66]; // 11616 floats
  int tid = threadIdx.x;
  int band = blockIdx.x % 13;
  int b    = blockIdx.x / 13;
  int r0 = band*20;
  for (int idx = tid; idx < 8*22*66; idx += 256){
    int lc = idx % 66;
    int rest = idx / 66;
    int lr = rest % 22;
    int ch = rest / 22;
    int gr = r0 - 1 + lr, gc = lc - 1;
    float v = 0.0f;
    if ((unsigned)gr < 250u && (unsigned)gc < 64u)
      v = in[((b*8+ch)*250+gr)*64+gc];
    tile[idx] = v;
  }
  __syncthreads();
  int dx = tid & 1; int u = tid >> 1;
  int pw = u & 31; int pr = (u >> 5) & 3;
  int cw = 2*pw + dx;
  int ph = band*4 + pr;
  float acc[5][16];
  #pragma unroll
  for (int dy=0;dy<5;dy++)
    #pragma unroll
    for (int o=0;o<16;o++) acc[dy][o] = 0.0f;
  int base = (5*pr)*66 + cw;
  #pragma unroll 1
  for (int c = 0; c < 8; ++c){
    float win[7][3];
    #pragma unroll
    for (int i=0;i<7;i++)
      #pragma unroll
      for (int j=0;j<3;j++)
        win[i][j] = tile[c*1452 + base + i*66 + j];
    #pragma unroll
    for (int kh=0;kh<3;kh++)
      #pragma unroll
      for (int kw=0;kw<3;kw++){
        float wv[16];
        #pragma unroll
        for (int o=0;o<16;o++) wv[o] = w2[((o*8+c)*3+kh)*3+kw];
        #pragma unroll
        for (int dy=0;dy<5;dy++){
          float v = win[dy+kh][kw];
          #pragma unroll
          for (int o=0;o<16;o++) acc[dy][o] = fmaf(v, wv[o], acc[dy][o]);
        }
      }
  }
  #pragma unroll
  for (int o=0;o<16;o++){
    float m = acc[0][o];
    #pragma unroll
    for (int dy=1;dy<5;dy++) m = fmaxf(m, acc[dy][o]);
    m = fmaxf(m, __shfl_xor(m, 1));
    if (dx == 0 && ph < 50) p2[((b*16+o)*50+ph)*32+pw] = lrelu(m);
  }
}

// =====================================================================
// conv3: conv(p2,w3,SAME 3x3, 16->32)+lrelu -> h3[32,32,50,32]
__global__ __launch_bounds__(256) void k_conv3(const float* __restrict__ in,
                                               const float* __restrict__ w3,
                                               float* __restrict__ outp){
  __shared__ float tile[16*10*34]; // 5440 floats
  int tid = threadIdx.x;
  int bi = blockIdx.x;
  int band = bi % 7; int oh = (bi/7) & 1; int b = bi / 14;
  int r0 = band*8;
  for (int idx = tid; idx < 16*10*34; idx += 256){
    int lc = idx % 34;
    int rest = idx / 34;
    int lr = rest % 10;
    int ch = rest / 10;
    int gr = r0 - 1 + lr, gc = lc - 1;
    float v = 0.0f;
    if ((unsigned)gr < 50u && (unsigned)gc < 32u)
      v = in[((b*16+ch)*50+gr)*32+gc];
    tile[idx] = v;
  }
  __syncthreads();
  int col = tid & 31, tr = tid >> 5;
  int h = r0 + tr;
  float acc[16];
  #pragma unroll
  for (int o=0;o<16;o++) acc[o] = 0.0f;
  int base = tr*34 + col;
  #pragma unroll 2
  for (int c = 0; c < 16; ++c){
    float win[3][3];
    #pragma unroll
    for (int i=0;i<3;i++)
      #pragma unroll
      for (int j=0;j<3;j++)
        win[i][j] = tile[c*340 + base + i*34 + j];
    #pragma unroll
    for (int kh=0;kh<3;kh++)
      #pragma unroll
      for (int kw=0;kw<3;kw++){
        float v = win[kh][kw];
        #pragma unroll
        for (int o=0;o<16;o++)
          acc[o] = fmaf(v, w3[(((oh*16+o)*16+c)*3+kh)*3+kw], acc[o]);
      }
  }
  if (h < 50){
    #pragma unroll
    for (int o=0;o<16;o++)
      outp[((b*32 + oh*16 + o)*50 + h)*32 + col] = lrelu(acc[o]);
  }
}

// =====================================================================
// pool3: maxpool(5,2) on h3 -> p3[32,32,10,16]
__global__ __launch_bounds__(256) void k_pool3(const float* __restrict__ in,
                                               float* __restrict__ outp){
  int t = blockIdx.x*256 + threadIdx.x;
  int pw = t & 15; int u = t >> 4; int ph = u % 10; u /= 10; int o = u & 31; int b = u >> 5;
  float m = -INFINITY;
  #pragma unroll
  for (int dh=0;dh<5;dh++)
    #pragma unroll
    for (int dw=0;dw<2;dw++)
      m = fmaxf(m, in[((b*32+o)*50 + 5*ph+dh)*32 + 2*pw+dw]);
  outp[((b*32+o)*10+ph)*16+pw] = m;
}

// =====================================================================
// latent: mu/logvar conv (1,5) VALID 32->1, reparameterize with threefry eps
__global__ __launch_bounds__(256) void k_latent(const float* __restrict__ p3,
                                                const float* __restrict__ wmu,
                                                const float* __restrict__ wlv,
                                                float* __restrict__ outp){
  int t = blockIdx.x*256 + threadIdx.x; // 3840 total
  int w = t % 12; int h = (t/12) % 10; int b = t/120;
  float mu = 0.0f, lv = 0.0f;
  for (int c = 0; c < 32; ++c){
    const float* row = p3 + ((b*32+c)*10+h)*16 + w;
    #pragma unroll
    for (int kw=0;kw<5;kw++){
      float v = row[kw];
      mu = fmaf(v, wmu[c*5+kw], mu);
      lv = fmaf(v, wlv[c*5+kw], lv);
    }
  }
  uint32_t x0 = 0u, x1 = (uint32_t)t;
  threefry_0_42(x0, x1);
  uint32_t bits = x0 ^ x1;
  float f = __uint_as_float((bits >> 9) | 0x3f800000u) - 1.0f; // [0,1)
  const float lo = -0.99999994f; // nextafter(-1,0) in f32; (1-lo) rounds to 2.0f
  float uu = fmaxf(lo, f * 2.0f + lo);
  float eps = 1.41421356f * erfinv_f32(uu);
  float z = mu + eps * expf(0.5f * lv);
  outp[OUT_MU_OFF + t] = mu;
  outp[OUT_LV_OFF + t] = lv;
  outp[OUT_Z_OFF  + t] = z;
}

// =====================================================================
// dec0: convT(z, wu0[32,1,1,5], stride 1, VALID) + lrelu -> d0[32,32,10,16]
__global__ __launch_bounds__(256) void k_dec0(const float* __restrict__ outp, // d_out base (z lives there)
                                              const float* __restrict__ wu0,
                                              float* __restrict__ d0){
  int t = blockIdx.x*256 + threadIdx.x;
  int w = t & 15; int u = t >> 4; int h = u % 10; u /= 10; int o = u & 31; int b = u >> 5;
  const float* z = outp + OUT_Z_OFF;
  float a = 0.0f;
  #pragma unroll
  for (int kw=0;kw<5;kw++){
    int ww = w + kw - 4;
    if ((unsigned)ww < 12u) a = fmaf(z[b*120 + h*12 + ww], wu0[o*5+kw], a);
  }
  d0[((b*32+o)*10+h)*16+w] = lrelu(a);
}

// =====================================================================
// dec1: convT(d0, wu1[32,32,5,2], strides (5,2)) + lrelu -> d1[32,32,50,32]
// one thread handles 8 output channels: input loaded once, reused.
__global__ __launch_bounds__(256) void k_dec1(const float* __restrict__ d0,
                                              const float* __restrict__ wu1,
                                              float* __restrict__ d1){
  int t = blockIdx.x*256 + threadIdx.x; // 32*50*32*4 = 204800 threads
  int wo = t & 31; int u = t >> 5; int ho = u % 50; u /= 50; int og = u & 3; int b = u >> 2;
  int i = ho / 5, r = ho - 5*i, jj = wo >> 1, s = wo & 1;
  const float* ip = d0 + b*5120 + i*16 + jj;             // + c*160
  float in[32];
  #pragma unroll
  for (int c=0;c<32;c++) in[c] = ip[c*160];
  #pragma unroll
  for (int oo=0;oo<8;oo++){
    int o = og*8 + oo;
    const float* wp = wu1 + (o*32*5 + (4-r))*2 + (1-s);  // + c*10
    float a = 0.0f;
    #pragma unroll
    for (int c=0;c<32;c++) a = fmaf(in[c], wp[c*10], a);
    d1[((b*32+o)*50+ho)*32+wo] = lrelu(a);
  }
}

// =====================================================================
// c4: conv(d1, w4[16,32,3,3], SAME)+lrelu -> d2[32,16,50,32]
__global__ __launch_bounds__(256) void k_c4(const float* __restrict__ in,
                                            const float* __restrict__ w4,
                                            float* __restrict__ outp){
  __shared__ float tile[32*10*34]; // 10880 floats
  int tid = threadIdx.x;
  int bi = blockIdx.x;
  int band = bi % 7; int oh = (bi/7) & 1; int b = bi / 14;
  int r0 = band*8;
  for (int idx = tid; idx < 32*10*34; idx += 256){
    int lc = idx % 34;
    int rest = idx / 34;
    int lr = rest % 10;
    int ch = rest / 10;
    int gr = r0 - 1 + lr, gc = lc - 1;
    float v = 0.0f;
    if ((unsigned)gr < 50u && (unsigned)gc < 32u)
      v = in[((b*32+ch)*50+gr)*32+gc];
    tile[idx] = v;
  }
  __syncthreads();
  int col = tid & 31, tr = tid >> 5;
  int h = r0 + tr;
  float acc[8];
  #pragma unroll
  for (int o=0;o<8;o++) acc[o] = 0.0f;
  int base = tr*34 + col;
  #pragma unroll 2
  for (int c = 0; c < 32; ++c){
    float win[3][3];
    #pragma unroll
    for (int i=0;i<3;i++)
      #pragma unroll
      for (int j=0;j<3;j++)
        win[i][j] = tile[c*340 + base + i*34 + j];
    #pragma unroll
    for (int kh=0;kh<3;kh++)
      #pragma unroll
      for (int kw=0;kw<3;kw++){
        float v = win[kh][kw];
        #pragma unroll
        for (int o=0;o<8;o++)
          acc[o] = fmaf(v, w4[(((oh*8+o)*32+c)*3+kh)*3+kw], acc[o]);
      }
  }
  if (h < 50){
    #pragma unroll
    for (int o=0;o<8;o++)
      outp[((b*16 + oh*8 + o)*50 + h)*32 + col] = lrelu(acc[o]);
  }
}

// =====================================================================
// u2: convT(d2, wu2[16,16,5,2], strides (5,2)) + lrelu -> d3[32,16,250,64]
// one thread handles all 16 output channels.
__global__ __launch_bounds__(256) void k_u2(const float* __restrict__ d2,
                                            const float* __restrict__ wu2,
                                            float* __restrict__ d3){
  int t = blockIdx.x*256 + threadIdx.x; // 32*250*64 = 512000 threads
  int w = t & 63; int u = t >> 6; int h = u % 250; int b = u / 250;
  int i = h / 5, r = h - 5*i, jj = w >> 1, s = w & 1;
  const float* ip = d2 + b*25600 + i*32 + jj;            // + c*1600
  float in[16];
  #pragma unroll
  for (int c=0;c<16;c++) in[c] = ip[c*1600];
  #pragma unroll
  for (int o=0;o<16;o++){
    const float* wp = wu2 + (o*16*5 + (4-r))*2 + (1-s);  // + c*10
    float a = 0.0f;
    #pragma unroll
    for (int c=0;c<16;c++) a = fmaf(in[c], wp[c*10], a);
    d3[((b*16+o)*250+h)*64+w] = lrelu(a);
  }
}

// =====================================================================
// c5: conv(d3, w5[8,16,3,3], SAME)+lrelu -> d4[32,8,250,64]
// 1x2 micro-tile: thread = (row, colpair), all 8 och. win[3][4] per ch.
// LDS tile: 8 rows (+2) x 64 cols (+2), 16 ch. grid = 32 bands x 32 b.
__global__ __launch_bounds__(256) void k_c5(const float* __restrict__ in,
                                            const float* __restrict__ w5,
                                            float* __restrict__ outp){
  __shared__ float tile[16*10*66]; // 10560 floats
  int tid = threadIdx.x;
  int band = blockIdx.x % 32;
  int b    = blockIdx.x / 32;
  int r0 = band*8;
  for (int idx = tid; idx < 16*10*66; idx += 256){
    int lc = idx % 66;
    int rest = idx / 66;
    int lr = rest % 10;
    int ch = rest / 10;
    int gr = r0 - 1 + lr, gc = lc - 1;
    float v = 0.0f;
    if ((unsigned)gr < 250u && (unsigned)gc < 64u)
      v = in[((b*16+ch)*250+gr)*64+gc];
    tile[idx] = v;
  }
  __syncthreads();
  int cp = tid & 31, tr = tid >> 5;   // cols {2cp, 2cp+1}, row r0+tr
  int h = r0 + tr;
  float acc[2][8];
  #pragma unroll
  for (int dx=0;dx<2;dx++)
    #pragma unroll
    for (int o=0;o<8;o++) acc[dx][o] = 0.0f;
  int base = tr*66 + 2*cp;
  #pragma unroll 2
  for (int c = 0; c < 16; ++c){
    float win[3][4];
    #pragma unroll
    for (int i=0;i<3;i++)
      #pragma unroll
      for (int j=0;j<4;j++)
        win[i][j] = tile[c*660 + base + i*66 + j];
    #pragma unroll
    for (int kh=0;kh<3;kh++)
      #pragma unroll
      for (int kw=0;kw<3;kw++){
        float wv[8];
        #pragma unroll
        for (int o=0;o<8;o++) wv[o] = w5[((o*16+c)*3+kh)*3+kw];
        #pragma unroll
        for (int dx=0;dx<2;dx++){
          float v = win[kh][dx+kw];
          #pragma unroll
          for (int o=0;o<8;o++) acc[dx][o] = fmaf(v, wv[o], acc[dx][o]);
        }
      }
  }
  if (h < 250){
    #pragma unroll
    for (int dx=0;dx<2;dx++)
      #pragma unroll
      for (int o=0;o<8;o++)
        outp[((b*8+o)*250+h)*64 + 2*cp+dx] = lrelu(acc[dx][o]);
  }
}

// =====================================================================
// u3: convT(d4, wu3[8,8,2,2], strides (2,2)) + lrelu -> d5[32,8,500,128]
// one thread handles all 8 output channels.
__global__ __launch_bounds__(256) void k_u3(const float* __restrict__ d4,
                                            const float* __restrict__ wu3,
                                            float* __restrict__ d5){
  int t = blockIdx.x*256 + threadIdx.x; // 32*500*128 = 2,048,000 threads
  int w = t & 127; int u = t >> 7; int h = u % 500; int b = u / 500;
  int i = h >> 1, r = h & 1, jj = w >> 1, s = w & 1;
  const float* ip = d4 + b*128000 + i*64 + jj;           // + c*16000
  float in[8];
  #pragma unroll
  for (int c=0;c<8;c++) in[c] = ip[c*16000];
  #pragma unroll
  for (int o=0;o<8;o++){
    const float* wp = wu3 + (o*8*2 + (1-r))*2 + (1-s);   // + c*4
    float a = 0.0f;
    #pragma unroll
    for (int c=0;c<8;c++) a = fmaf(in[c], wp[c*4], a);
    d5[((b*8+o)*500+h)*128+w] = lrelu(a);
  }
}

// =====================================================================
// c6: conv(d5, w6[6,8,3,3], SAME)+lrelu -> d_out[32,6,500,128]
// 2x2 micro-tile: thread = (rowpair, colpair), all 6 och. win[4][4] per ch.
// LDS tile: 8 rows (+2) x 128 cols (+2), 8 ch. grid = 63 bands x 32 b.
__global__ __launch_bounds__(256) void k_c6(const float* __restrict__ in,
                                            const float* __restrict__ w6,
                                            float* __restrict__ outp){
  __shared__ float tile[8*10*130]; // 10400 floats
  int tid = threadIdx.x;
  int band = blockIdx.x % 63;
  int b    = blockIdx.x / 63;
  int r0 = band*8;
  for (int idx = tid; idx < 8*10*130; idx += 256){
    int lc = idx % 130;
    int rest = idx / 130;
    int lr = rest % 10;
    int ch = rest / 10;
    int gr = r0 - 1 + lr, gc = lc - 1;
    float v = 0.0f;
    if ((unsigned)gr < 500u && (unsigned)gc < 128u)
      v = in[((b*8+ch)*500+gr)*128+gc];
    tile[idx] = v;
  }
  __syncthreads();
  int cp = tid & 63, rp = tid >> 6;  // cols {2cp,2cp+1}, rows r0+{2rp,2rp+1}
  float acc[2][2][6];
  #pragma unroll
  for (int dy=0;dy<2;dy++)
    #pragma unroll
    for (int dx=0;dx<2;dx++)
      #pragma unroll
      for (int o=0;o<6;o++) acc[dy][dx][o] = 0.0f;
  int base = (2*rp)*130 + 2*cp;
  #pragma unroll 2
  for (int c = 0; c < 8; ++c){
    float win[4][4];
    #pragma unroll
    for (int i=0;i<4;i++)
      #pragma unroll
      for (int j=0;j<4;j++)
        win[i][j] = tile[c*1300 + base + i*130 + j];
    #pragma unroll
    for (int kh=0;kh<3;kh++)
      #pragma unroll
      for (int kw=0;kw<3;kw++){
        float wv[6];
        #pragma unroll
        for (int o=0;o<6;o++) wv[o] = w6[((o*8+c)*3+kh)*3+kw];
        #pragma unroll
        for (int dy=0;dy<2;dy++)
          #pragma unroll
          for (int dx=0;dx<2;dx++){
            float v = win[dy+kh][dx+kw];
            #pragma unroll
            for (int o=0;o<6;o++) acc[dy][dx][o] = fmaf(v, wv[o], acc[dy][dx][o]);
          }
      }
  }
  #pragma unroll
  for (int dy=0;dy<2;dy++){
    int h = r0 + 2*rp + dy;
    if (h < 500){
      #pragma unroll
      for (int dx=0;dx<2;dx++)
        #pragma unroll
        for (int o=0;o<6;o++)
          outp[((b*6+o)*500+h)*128 + 2*cp+dx] = lrelu(acc[dy][dx][o]);
    }
  }
}

// =====================================================================
extern "C" void kernel_launch(void* const* d_in, const int* in_sizes, int n_in,
                              void* d_out, int out_size, void* d_ws, size_t ws_size,
                              hipStream_t stream){
  const float* x   = (const float*)d_in[0];
  const float* w1  = (const float*)d_in[1];
  const float* w2  = (const float*)d_in[2];
  const float* w3  = (const float*)d_in[3];
  const float* wmu = (const float*)d_in[4];
  const float* wlv = (const float*)d_in[5];
  const float* wu0 = (const float*)d_in[6];
  const float* wu1 = (const float*)d_in[7];
  const float* w4  = (const float*)d_in[8];
  const float* wu2 = (const float*)d_in[9];
  const float* w5  = (const float*)d_in[10];
  const float* wu3 = (const float*)d_in[11];
  const float* w6  = (const float*)d_in[12];
  float* out = (float*)d_out;
  float* A  = (float*)d_ws;          // 4,096,000 floats arena
  float* Bb = A + 4096000;           // 16,384,000 floats arena

  k_enc1 <<<2016, 256, 0, stream>>>(x,  w1,  A);   // p1 [32,8,250,64]
  k_enc2 <<< 416, 256, 0, stream>>>(A,  w2,  Bb);  // p2 [32,16,50,32]
  k_conv3<<< 448, 256, 0, stream>>>(Bb, w3,  A);   // h3 [32,32,50,32]
  k_pool3<<< 640, 256, 0, stream>>>(A,  Bb);       // p3 [32,32,10,16]
  k_latent<<< 15, 256, 0, stream>>>(Bb, wmu, wlv, out); // mu/lv/z -> d_out
  k_dec0 <<< 640, 256, 0, stream>>>(out, wu0, A);  // d0 [32,32,10,16]
  k_dec1 <<< 800, 256, 0, stream>>>(A,  wu1, Bb);  // d1 [32,32,50,32]
  k_c4   <<< 448, 256, 0, stream>>>(Bb, w4,  A);   // d2 [32,16,50,32]
  k_u2   <<<2000, 256, 0, stream>>>(A,  wu2, Bb);  // d3 [32,16,250,64]
  k_c5   <<<1024, 256, 0, stream>>>(Bb, w5,  A);   // d4 [32,8,250,64]
  k_u3   <<<8000, 256, 0, stream>>>(A,  wu3, Bb);  // d5 [32,8,500,128]
  k_c6   <<<2016, 256, 0, stream>>>(Bb, w6,  out); // d  [32,6,500,128]
}

// Round 6
// 380.976 us; speedup vs baseline: 1.1931x; 1.1346x over previous
//
#include <hip/hip_runtime.h>
#include <stdint.h>

#define DI __device__ __forceinline__

DI float lrelu(float x){ return x >= 0.0f ? x : 0.01f*x; }

// ---------------- threefry2x32, JAX key(42) => (0, 42) ----------------
DI uint32_t rotl32(uint32_t x, int d){ return (x << d) | (x >> (32 - d)); }

DI void threefry_0_42(uint32_t& x0, uint32_t& x1){
  const uint32_t ks0 = 0u, ks1 = 42u, ks2 = 0x1BD11BF0u; // 0 ^ 42 ^ 0x1BD11BDA
  x0 += ks0; x1 += ks1;
  #define TFR(d) { x0 += x1; x1 = rotl32(x1,(d)); x1 ^= x0; }
  TFR(13) TFR(15) TFR(26) TFR(6)  x0 += ks1; x1 += ks2 + 1u;
  TFR(17) TFR(29) TFR(16) TFR(24) x0 += ks2; x1 += ks0 + 2u;
  TFR(13) TFR(15) TFR(26) TFR(6)  x0 += ks0; x1 += ks1 + 3u;
  TFR(17) TFR(29) TFR(16) TFR(24) x0 += ks1; x1 += ks2 + 4u;
  TFR(13) TFR(15) TFR(26) TFR(6)  x0 += ks2; x1 += ks0 + 5u;
  #undef TFR
}

// XLA/Giles single-precision erfinv (same coefficients as chlo erf_inv f32)
DI float erfinv_f32(float x){
  float w = -log1pf(-x*x);
  float p;
  if (w < 5.0f){
    w = w - 2.5f;
    p = 2.81022636e-08f;
    p = fmaf(p, w, 3.43273939e-07f);
    p = fmaf(p, w, -3.5233877e-06f);
    p = fmaf(p, w, -4.39150654e-06f);
    p = fmaf(p, w, 0.00021858087f);
    p = fmaf(p, w, -0.00125372503f);
    p = fmaf(p, w, -0.00417768164f);
    p = fmaf(p, w, 0.246640727f);
    p = fmaf(p, w, 1.50140941f);
  } else {
    w = sqrtf(w) - 3.0f;
    p = -0.000200214257f;
    p = fmaf(p, w, 0.000100950558f);
    p = fmaf(p, w, 0.00134934322f);
    p = fmaf(p, w, -0.00367342844f);
    p = fmaf(p, w, 0.00573950773f);
    p = fmaf(p, w, -0.0076224613f);
    p = fmaf(p, w, 0.00943887047f);
    p = fmaf(p, w, 1.00167406f);
    p = fmaf(p, w, 2.83297682f);
  }
  return p * x;
}

// out offsets (floats)
#define OUT_D_OFF   0
#define OUT_MU_OFF  12288000
#define OUT_LV_OFF  (12288000 + 3840)
#define OUT_Z_OFF   (12288000 + 7680)

// =====================================================================
// enc1: conv(x,w1,SAME 3x3, 6->8)+lrelu+maxpool 2x2 -> p1[32,8,250,64]
__global__ __launch_bounds__(256) void k_enc1(const float* __restrict__ x,
                                              const float* __restrict__ w1,
                                              float* __restrict__ p1){
  __shared__ float tile[6*10*130]; // 7800 floats
  int tid = threadIdx.x;
  int band = blockIdx.x % 63;
  int b    = blockIdx.x / 63;
  int r0 = band*8;
  for (int idx = tid; idx < 6*10*130; idx += 256){
    int lc = idx % 130;
    int rest = idx / 130;
    int lr = rest % 10;
    int ch = rest / 10;
    int gr = r0 - 1 + lr, gc = lc - 1;
    float v = 0.0f;
    if ((unsigned)gr < 500u && (unsigned)gc < 128u)
      v = x[((b*6+ch)*500+gr)*128+gc];
    tile[idx] = v;
  }
  __syncthreads();
  int pw = tid & 63, pr = tid >> 6;
  int ph = band*4 + pr;
  float acc[2][2][8];
  #pragma unroll
  for (int a=0;a<2;a++)
    #pragma unroll
    for (int d=0;d<2;d++)
      #pragma unroll
      for (int o=0;o<8;o++) acc[a][d][o] = 0.0f;
  int base = (2*pr)*130 + 2*pw;
  #pragma unroll 2
  for (int c = 0; c < 6; ++c){
    float win[4][4];
    #pragma unroll
    for (int i=0;i<4;i++)
      #pragma unroll
      for (int j=0;j<4;j++)
        win[i][j] = tile[c*1300 + base + i*130 + j];
    #pragma unroll
    for (int kh=0;kh<3;kh++)
      #pragma unroll
      for (int kw=0;kw<3;kw++){
        float wv[8];
        #pragma unroll
        for (int o=0;o<8;o++) wv[o] = w1[((o*6+c)*3+kh)*3+kw];
        #pragma unroll
        for (int dy=0;dy<2;dy++)
          #pragma unroll
          for (int dx=0;dx<2;dx++){
            float v = win[dy+kh][dx+kw];
            #pragma unroll
            for (int o=0;o<8;o++) acc[dy][dx][o] = fmaf(v, wv[o], acc[dy][dx][o]);
          }
      }
  }
  if (ph < 250){
    #pragma unroll
    for (int o=0;o<8;o++){
      float m = fmaxf(fmaxf(acc[0][0][o], acc[0][1][o]), fmaxf(acc[1][0][o], acc[1][1][o]));
      p1[((b*8+o)*250+ph)*64+pw] = lrelu(m);
    }
  }
}

// =====================================================================
// enc2: conv(p1,w2,SAME 3x3, 8->16)+lrelu+maxpool(5,2) -> p2[32,16,50,32]
__global__ __launch_bounds__(256) void k_enc2(const float* __restrict__ in,
                                              const float* __restrict__ w2,
                                              float* __restrict__ p2){
  __shared__ float tile[8*22*66]; // 11616 floats
  int tid = threadIdx.x;
  int band = blockIdx.x % 13;
  int b    = blockIdx.x / 13;
  int r0 = band*20;
  for (int idx = tid; idx < 8*22*66; idx += 256){
    int lc = idx % 66;
    int rest = idx / 66;
    int lr = rest % 22;
    int ch = rest / 22;
    int gr = r0 - 1 + lr, gc = lc - 1;
    float v = 0.0f;
    if ((unsigned)gr < 250u && (unsigned)gc < 64u)
      v = in[((b*8+ch)*250+gr)*64+gc];
    tile[idx] = v;
  }
  __syncthreads();
  int dx = tid & 1; int u = tid >> 1;
  int pw = u & 31; int pr = (u >> 5) & 3;
  int cw = 2*pw + dx;
  int ph = band*4 + pr;
  float acc[5][16];
  #pragma unroll
  for (int dy=0;dy<5;dy++)
    #pragma unroll
    for (int o=0;o<16;o++) acc[dy][o] = 0.0f;
  int base = (5*pr)*66 + cw;
  #pragma unroll 1
  for (int c = 0; c < 8; ++c){
    float win[7][3];
    #pragma unroll
    for (int i=0;i<7;i++)
      #pragma unroll
      for (int j=0;j<3;j++)
        win[i][j] = tile[c*1452 + base + i*66 + j];
    #pragma unroll
    for (int kh=0;kh<3;kh++)
      #pragma unroll
      for (int kw=0;kw<3;kw++){
        float wv[16];
        #pragma unroll
        for (int o=0;o<16;o++) wv[o] = w2[((o*8+c)*3+kh)*3+kw];
        #pragma unroll
        for (int dy=0;dy<5;dy++){
          float v = win[dy+kh][kw];
          #pragma unroll
          for (int o=0;o<16;o++) acc[dy][o] = fmaf(v, wv[o], acc[dy][o]);
        }
      }
  }
  #pragma unroll
  for (int o=0;o<16;o++){
    float m = acc[0][o];
    #pragma unroll
    for (int dy=1;dy<5;dy++) m = fmaxf(m, acc[dy][o]);
    m = fmaxf(m, __shfl_xor(m, 1));
    if (dx == 0 && ph < 50) p2[((b*16+o)*50+ph)*32+pw] = lrelu(m);
  }
}

// =====================================================================
// conv3: conv(p2,w3,SAME 3x3, 16->32)+lrelu -> h3[32,32,50,32]
__global__ __launch_bounds__(256) void k_conv3(const float* __restrict__ in,
                                               const float* __restrict__ w3,
                                               float* __restrict__ outp){
  __shared__ float tile[16*10*34]; // 5440 floats
  int tid = threadIdx.x;
  int bi = blockIdx.x;
  int band = bi % 7; int oh = (bi/7) & 1; int b = bi / 14;
  int r0 = band*8;
  for (int idx = tid; idx < 16*10*34; idx += 256){
    int lc = idx % 34;
    int rest = idx / 34;
    int lr = rest % 10;
    int ch = rest / 10;
    int gr = r0 - 1 + lr, gc = lc - 1;
    float v = 0.0f;
    if ((unsigned)gr < 50u && (unsigned)gc < 32u)
      v = in[((b*16+ch)*50+gr)*32+gc];
    tile[idx] = v;
  }
  __syncthreads();
  int col = tid & 31, tr = tid >> 5;
  int h = r0 + tr;
  float acc[16];
  #pragma unroll
  for (int o=0;o<16;o++) acc[o] = 0.0f;
  int base = tr*34 + col;
  #pragma unroll 2
  for (int c = 0; c < 16; ++c){
    float win[3][3];
    #pragma unroll
    for (int i=0;i<3;i++)
      #pragma unroll
      for (int j=0;j<3;j++)
        win[i][j] = tile[c*340 + base + i*34 + j];
    #pragma unroll
    for (int kh=0;kh<3;kh++)
      #pragma unroll
      for (int kw=0;kw<3;kw++){
        float v = win[kh][kw];
        #pragma unroll
        for (int o=0;o<16;o++)
          acc[o] = fmaf(v, w3[(((oh*16+o)*16+c)*3+kh)*3+kw], acc[o]);
      }
  }
  if (h < 50){
    #pragma unroll
    for (int o=0;o<16;o++)
      outp[((b*32 + oh*16 + o)*50 + h)*32 + col] = lrelu(acc[o]);
  }
}

// =====================================================================
// pool3: maxpool(5,2) on h3 -> p3[32,32,10,16]
__global__ __launch_bounds__(256) void k_pool3(const float* __restrict__ in,
                                               float* __restrict__ outp){
  int t = blockIdx.x*256 + threadIdx.x;
  int pw = t & 15; int u = t >> 4; int ph = u % 10; u /= 10; int o = u & 31; int b = u >> 5;
  float m = -INFINITY;
  #pragma unroll
  for (int dh=0;dh<5;dh++)
    #pragma unroll
    for (int dw=0;dw<2;dw++)
      m = fmaxf(m, in[((b*32+o)*50 + 5*ph+dh)*32 + 2*pw+dw]);
  outp[((b*32+o)*10+ph)*16+pw] = m;
}

// =====================================================================
// latent: mu/logvar conv (1,5) VALID 32->1, reparameterize with threefry eps
__global__ __launch_bounds__(256) void k_latent(const float* __restrict__ p3,
                                                const float* __restrict__ wmu,
                                                const float* __restrict__ wlv,
                                                float* __restrict__ outp){
  int t = blockIdx.x*256 + threadIdx.x; // 3840 total
  int w = t % 12; int h = (t/12) % 10; int b = t/120;
  float mu = 0.0f, lv = 0.0f;
  for (int c = 0; c < 32; ++c){
    const float* row = p3 + ((b*32+c)*10+h)*16 + w;
    #pragma unroll
    for (int kw=0;kw<5;kw++){
      float v = row[kw];
      mu = fmaf(v, wmu[c*5+kw], mu);
      lv = fmaf(v, wlv[c*5+kw], lv);
    }
  }
  uint32_t x0 = 0u, x1 = (uint32_t)t;
  threefry_0_42(x0, x1);
  uint32_t bits = x0 ^ x1;
  float f = __uint_as_float((bits >> 9) | 0x3f800000u) - 1.0f; // [0,1)
  const float lo = -0.99999994f; // nextafter(-1,0) in f32; (1-lo) rounds to 2.0f
  float uu = fmaxf(lo, f * 2.0f + lo);
  float eps = 1.41421356f * erfinv_f32(uu);
  float z = mu + eps * expf(0.5f * lv);
  outp[OUT_MU_OFF + t] = mu;
  outp[OUT_LV_OFF + t] = lv;
  outp[OUT_Z_OFF  + t] = z;
}

// =====================================================================
// dec0: convT(z, wu0[32,1,1,5], stride 1, VALID) + lrelu -> d0[32,32,10,16]
__global__ __launch_bounds__(256) void k_dec0(const float* __restrict__ outp, // d_out base (z lives there)
                                              const float* __restrict__ wu0,
                                              float* __restrict__ d0){
  int t = blockIdx.x*256 + threadIdx.x;
  int w = t & 15; int u = t >> 4; int h = u % 10; u /= 10; int o = u & 31; int b = u >> 5;
  const float* z = outp + OUT_Z_OFF;
  float a = 0.0f;
  #pragma unroll
  for (int kw=0;kw<5;kw++){
    int ww = w + kw - 4;
    if ((unsigned)ww < 12u) a = fmaf(z[b*120 + h*12 + ww], wu0[o*5+kw], a);
  }
  d0[((b*32+o)*10+h)*16+w] = lrelu(a);
}

// =====================================================================
// dec1: convT(d0, wu1[32,32,5,2], strides (5,2)) + lrelu -> d1[32,32,50,32]
__global__ __launch_bounds__(256) void k_dec1(const float* __restrict__ d0,
                                              const float* __restrict__ wu1,
                                              float* __restrict__ d1){
  int t = blockIdx.x*256 + threadIdx.x; // 32*50*32*4 = 204800 threads
  int wo = t & 31; int u = t >> 5; int ho = u % 50; u /= 50; int og = u & 3; int b = u >> 2;
  int i = ho / 5, r = ho - 5*i, jj = wo >> 1, s = wo & 1;
  const float* ip = d0 + b*5120 + i*16 + jj;             // + c*160
  float in[32];
  #pragma unroll
  for (int c=0;c<32;c++) in[c] = ip[c*160];
  #pragma unroll
  for (int oo=0;oo<8;oo++){
    int o = og*8 + oo;
    const float* wp = wu1 + (o*32*5 + (4-r))*2 + (1-s);  // + c*10
    float a = 0.0f;
    #pragma unroll
    for (int c=0;c<32;c++) a = fmaf(in[c], wp[c*10], a);
    d1[((b*32+o)*50+ho)*32+wo] = lrelu(a);
  }
}

// =====================================================================
// c4: conv(d1, w4[16,32,3,3], SAME)+lrelu -> d2[32,16,50,32]
__global__ __launch_bounds__(256) void k_c4(const float* __restrict__ in,
                                            const float* __restrict__ w4,
                                            float* __restrict__ outp){
  __shared__ float tile[32*10*34]; // 10880 floats
  int tid = threadIdx.x;
  int bi = blockIdx.x;
  int band = bi % 7; int oh = (bi/7) & 1; int b = bi / 14;
  int r0 = band*8;
  for (int idx = tid; idx < 32*10*34; idx += 256){
    int lc = idx % 34;
    int rest = idx / 34;
    int lr = rest % 10;
    int ch = rest / 10;
    int gr = r0 - 1 + lr, gc = lc - 1;
    float v = 0.0f;
    if ((unsigned)gr < 50u && (unsigned)gc < 32u)
      v = in[((b*32+ch)*50+gr)*32+gc];
    tile[idx] = v;
  }
  __syncthreads();
  int col = tid & 31, tr = tid >> 5;
  int h = r0 + tr;
  float acc[8];
  #pragma unroll
  for (int o=0;o<8;o++) acc[o] = 0.0f;
  int base = tr*34 + col;
  #pragma unroll 2
  for (int c = 0; c < 32; ++c){
    float win[3][3];
    #pragma unroll
    for (int i=0;i<3;i++)
      #pragma unroll
      for (int j=0;j<3;j++)
        win[i][j] = tile[c*340 + base + i*34 + j];
    #pragma unroll
    for (int kh=0;kh<3;kh++)
      #pragma unroll
      for (int kw=0;kw<3;kw++){
        float v = win[kh][kw];
        #pragma unroll
        for (int o=0;o<8;o++)
          acc[o] = fmaf(v, w4[(((oh*8+o)*32+c)*3+kh)*3+kw], acc[o]);
      }
  }
  if (h < 50){
    #pragma unroll
    for (int o=0;o<8;o++)
      outp[((b*16 + oh*8 + o)*50 + h)*32 + col] = lrelu(acc[o]);
  }
}

// =====================================================================
// u2: convT(d2, wu2[16,16,5,2], strides (5,2)) + lrelu -> d3[32,16,250,64]
__global__ __launch_bounds__(256) void k_u2(const float* __restrict__ d2,
                                            const float* __restrict__ wu2,
                                            float* __restrict__ d3){
  int t = blockIdx.x*256 + threadIdx.x; // 32*250*64 = 512000 threads
  int w = t & 63; int u = t >> 6; int h = u % 250; int b = u / 250;
  int i = h / 5, r = h - 5*i, jj = w >> 1, s = w & 1;
  const float* ip = d2 + b*25600 + i*32 + jj;            // + c*1600
  float in[16];
  #pragma unroll
  for (int c=0;c<16;c++) in[c] = ip[c*1600];
  #pragma unroll
  for (int o=0;o<16;o++){
    const float* wp = wu2 + (o*16*5 + (4-r))*2 + (1-s);  // + c*10
    float a = 0.0f;
    #pragma unroll
    for (int c=0;c<16;c++) a = fmaf(in[c], wp[c*10], a);
    d3[((b*16+o)*250+h)*64+w] = lrelu(a);
  }
}

// =====================================================================
// c5: conv(d3, w5[8,16,3,3], SAME)+lrelu -> d4[32,8,250,64]
__global__ __launch_bounds__(256) void k_c5(const float* __restrict__ in,
                                            const float* __restrict__ w5,
                                            float* __restrict__ outp){
  __shared__ float tile[16*10*66]; // 10560 floats
  int tid = threadIdx.x;
  int band = blockIdx.x % 32;
  int b    = blockIdx.x / 32;
  int r0 = band*8;
  for (int idx = tid; idx < 16*10*66; idx += 256){
    int lc = idx % 66;
    int rest = idx / 66;
    int lr = rest % 10;
    int ch = rest / 10;
    int gr = r0 - 1 + lr, gc = lc - 1;
    float v = 0.0f;
    if ((unsigned)gr < 250u && (unsigned)gc < 64u)
      v = in[((b*16+ch)*250+gr)*64+gc];
    tile[idx] = v;
  }
  __syncthreads();
  int cp = tid & 31, tr = tid >> 5;   // cols {2cp, 2cp+1}, row r0+tr
  int h = r0 + tr;
  float acc[2][8];
  #pragma unroll
  for (int dx=0;dx<2;dx++)
    #pragma unroll
    for (int o=0;o<8;o++) acc[dx][o] = 0.0f;
  int base = tr*66 + 2*cp;
  #pragma unroll 2
  for (int c = 0; c < 16; ++c){
    float win[3][4];
    #pragma unroll
    for (int i=0;i<3;i++)
      #pragma unroll
      for (int j=0;j<4;j++)
        win[i][j] = tile[c*660 + base + i*66 + j];
    #pragma unroll
    for (int kh=0;kh<3;kh++)
      #pragma unroll
      for (int kw=0;kw<3;kw++){
        float wv[8];
        #pragma unroll
        for (int o=0;o<8;o++) wv[o] = w5[((o*16+c)*3+kh)*3+kw];
        #pragma unroll
        for (int dx=0;dx<2;dx++){
          float v = win[kh][dx+kw];
          #pragma unroll
          for (int o=0;o<8;o++) acc[dx][o] = fmaf(v, wv[o], acc[dx][o]);
        }
      }
  }
  if (h < 250){
    #pragma unroll
    for (int dx=0;dx<2;dx++)
      #pragma unroll
      for (int o=0;o<8;o++)
        outp[((b*8+o)*250+h)*64 + 2*cp+dx] = lrelu(acc[dx][o]);
  }
}

// =====================================================================
// u3c6 FUSED: d5 = convT(d4, wu3[8,8,2,2], (2,2))+lrelu computed into LDS
// band (phase A), then conv(d5, w6[6,8,3,3], SAME)+lrelu -> out (phase B).
// d5 tile layout per (ch,lr): positions 0..127 = cols 0..127, 128 = zero
// (right halo), 129 = zero (left halo col -1); row stride 132 keeps b128
// reads/writes 16B-aligned. Band = 8 out rows (+2 halo d5 rows).
// grid = 63 bands x 32 batch, 256 thr.
__global__ __launch_bounds__(256) void k_u3c6(const float* __restrict__ d4,
                                              const float* __restrict__ wu3,
                                              const float* __restrict__ w6,
                                              float* __restrict__ outp){
  __shared__ __align__(16) float dt[8*10*132]; // 42240 B
  __shared__ __align__(16) float wl[256];      // wu3 copy
  int tid = threadIdx.x;
  int band = blockIdx.x % 63;
  int b    = blockIdx.x / 63;
  int r0 = band*8;
  wl[tid] = wu3[tid];
  if (tid < 80){
    int ch = tid / 10, lr = tid % 10;
    dt[(ch*10+lr)*132 + 128] = 0.0f;
    dt[(ch*10+lr)*132 + 129] = 0.0f;
  }
  __syncthreads();
  // ---- phase A: build d5 band rows r0-1 .. r0+8 ----
  for (int s = tid; s < 320; s += 256){
    int q = s & 31, lr = s >> 5;
    int h = r0 - 1 + lr;               // d5 row
    if ((unsigned)h < 500u){
      int i2 = h >> 1, r = h & 1;
      float2 dv[8];
      #pragma unroll
      for (int c=0;c<8;c++)
        dv[c] = *(const float2*)(d4 + ((b*8+c)*250 + i2)*64 + 2*q);
      int wbase = (1-r)*2;
      #pragma unroll
      for (int o5=0;o5<8;o5++){
        float a0=0.f,a1=0.f,a2=0.f,a3=0.f;
        #pragma unroll
        for (int c=0;c<8;c++){
          float2 wp = *(const float2*)(wl + o5*32 + c*4 + wbase);
          // wp.x = weight for (1-sp)=0 i.e. sp=1; wp.y = sp=0
          a0 = fmaf(dv[c].x, wp.y, a0);  // col 4q+0: jj=2q, sp=0
          a1 = fmaf(dv[c].x, wp.x, a1);  // col 4q+1: jj=2q, sp=1
          a2 = fmaf(dv[c].y, wp.y, a2);  // col 4q+2: jj=2q+1, sp=0
          a3 = fmaf(dv[c].y, wp.x, a3);  // col 4q+3: jj=2q+1, sp=1
        }
        float4 v4 = make_float4(lrelu(a0), lrelu(a1), lrelu(a2), lrelu(a3));
        *(float4*)(dt + (o5*10+lr)*132 + 4*q) = v4;
      }
    } else {
      float4 z = make_float4(0.f,0.f,0.f,0.f);
      #pragma unroll
      for (int o5=0;o5<8;o5++)
        *(float4*)(dt + (o5*10+lr)*132 + 4*q) = z;
    }
  }
  __syncthreads();
  // ---- phase B: conv 3x3 8->6 over the d5 band ----
  int q = tid & 31, tr = tid >> 5;     // cols 4q..4q+3, out row r0+tr
  int R = r0 + tr;
  float acc[4][6];
  #pragma unroll
  for (int j=0;j<4;j++)
    #pragma unroll
    for (int o=0;o<6;o++) acc[j][o] = 0.0f;
  int left = (q==0) ? 129 : (4*q - 1);
  #pragma unroll 2
  for (int ch=0; ch<8; ++ch){
    #pragma unroll
    for (int wr=0; wr<3; ++wr){
      const float* row = dt + (ch*10 + tr + wr)*132;
      float win[6];
      float4 m = *(const float4*)(row + 4*q);
      win[0] = row[left];
      win[1] = m.x; win[2] = m.y; win[3] = m.z; win[4] = m.w;
      win[5] = row[4*q + 4];
      #pragma unroll
      for (int kw=0;kw<3;kw++){
        #pragma unroll
        for (int o=0;o<6;o++){
          float wv = w6[((o*8+ch)*3+wr)*3+kw];
          #pragma unroll
          for (int j=0;j<4;j++)
            acc[j][o] = fmaf(win[j+kw], wv, acc[j][o]);
        }
      }
    }
  }
  if (R < 500){
    #pragma unroll
    for (int o=0;o<6;o++){
      float4 v = make_float4(lrelu(acc[0][o]), lrelu(acc[1][o]),
                             lrelu(acc[2][o]), lrelu(acc[3][o]));
      *(float4*)(outp + ((b*6+o)*500 + R)*128 + 4*q) = v;
    }
  }
}

// =====================================================================
extern "C" void kernel_launch(void* const* d_in, const int* in_sizes, int n_in,
                              void* d_out, int out_size, void* d_ws, size_t ws_size,
                              hipStream_t stream){
  const float* x   = (const float*)d_in[0];
  const float* w1  = (const float*)d_in[1];
  const float* w2  = (const float*)d_in[2];
  const float* w3  = (const float*)d_in[3];
  const float* wmu = (const float*)d_in[4];
  const float* wlv = (const float*)d_in[5];
  const float* wu0 = (const float*)d_in[6];
  const float* wu1 = (const float*)d_in[7];
  const float* w4  = (const float*)d_in[8];
  const float* wu2 = (const float*)d_in[9];
  const float* w5  = (const float*)d_in[10];
  const float* wu3 = (const float*)d_in[11];
  const float* w6  = (const float*)d_in[12];
  float* out = (float*)d_out;
  float* A  = (float*)d_ws;          // 4,096,000 floats arena
  float* Bb = A + 4096000;           // 16,384,000 floats arena

  k_enc1 <<<2016, 256, 0, stream>>>(x,  w1,  A);   // p1 [32,8,250,64]
  k_enc2 <<< 416, 256, 0, stream>>>(A,  w2,  Bb);  // p2 [32,16,50,32]
  k_conv3<<< 448, 256, 0, stream>>>(Bb, w3,  A);   // h3 [32,32,50,32]
  k_pool3<<< 640, 256, 0, stream>>>(A,  Bb);       // p3 [32,32,10,16]
  k_latent<<< 15, 256, 0, stream>>>(Bb, wmu, wlv, out); // mu/lv/z -> d_out
  k_dec0 <<< 640, 256, 0, stream>>>(out, wu0, A);  // d0 [32,32,10,16]
  k_dec1 <<< 800, 256, 0, stream>>>(A,  wu1, Bb);  // d1 [32,32,50,32]
  k_c4   <<< 448, 256, 0, stream>>>(Bb, w4,  A);   // d2 [32,16,50,32]
  k_u2   <<<2000, 256, 0, stream>>>(A,  wu2, Bb);  // d3 [32,16,250,64]
  k_c5   <<<1024, 256, 0, stream>>>(Bb, w5,  A);   // d4 [32,8,250,64]
  k_u3c6 <<<2016, 256, 0, stream>>>(A, wu3, w6, out); // d [32,6,500,128]
}